// Round 4
// baseline (149.814 us; speedup 1.0000x reference)
//
#include <hip/hip_runtime.h>

// RandRotate90_3D: per-sample rot90^k (k = koefs[b] in [0,3]) on axes (D,H)
// of [B=16, D=128, H=128, W=128] float32, applied to 3 tensors.
// Closed form of the reference's iterative masked-rot90:
//   k=0: out[i][j] = in[i][j]
//   k=1: out[i][j] = in[j][127-i]
//   k=2: out[i][j] = in[127-i][127-j]
//   k=3: out[i][j] = in[127-j][i]
// W axis untouched -> all accesses are 512B-contiguous rows. Pure gather.
// R4: hoist invariant index math. Grid-stride step is 2^19 float4 == one
// sample, so (i,j,w4) are per-thread constants; only (b,t) advance per iter.
// Precompute off[b] for all 16 samples (fully unrolled -> registers), then
// the hot loop is load+store with immediate offsets. unroll 8 -> 8 loads in
// flight. Non-temporal both sides (805MB streaming, zero reuse).

typedef float f32x4 __attribute__((ext_vector_type(4)));

#define NN 128
#define W4 32                        // 128 floats / 4 per float4
#define SAMPLE (NN * NN * W4)        // 2^19 float4 per sample
#define PER_TENSOR (16 * SAMPLE)     // 2^23 float4 per tensor
#define TPB 256
#define BLOCKS 2048                  // 524288 threads == SAMPLE

__global__ __launch_bounds__(TPB) void rot90_gather_kernel(
    const f32x4* __restrict__ vol,
    const f32x4* __restrict__ msk,
    const f32x4* __restrict__ skl,
    const int* __restrict__ koefs,
    f32x4* __restrict__ out)
{
    const int tid = blockIdx.x * TPB + threadIdx.x;   // [0, 2^19)
    const int i  = (tid >> 12) & 127;
    const int j  = (tid >> 5) & 127;
    const int w4 = tid & 31;

    // 4 candidate per-sample source offsets (float4 units)
    const int s0 = (i * NN + j) * W4 + w4;
    const int s1 = (j * NN + (127 - i)) * W4 + w4;
    const int s2 = ((127 - i) * NN + (127 - j)) * W4 + w4;
    const int s3 = ((127 - j) * NN + i) * W4 + w4;

    // resolve once per sample; constant indices after unroll -> registers
    int off[16];
#pragma unroll
    for (int b = 0; b < 16; ++b) {
        const int k = koefs[b];   // wave-uniform scalar load
        off[b] = (k == 1 ? s1 : k == 2 ? s2 : k == 3 ? s3 : s0) + b * SAMPLE;
    }

#pragma unroll
    for (int t = 0; t < 3; ++t) {
        const f32x4* __restrict__ in = (t == 0) ? vol : (t == 1) ? msk : skl;
        f32x4* __restrict__ o = out + t * PER_TENSOR + tid;
#pragma unroll 8
        for (int b = 0; b < 16; ++b) {
            const f32x4 v = __builtin_nontemporal_load(in + off[b]);
            __builtin_nontemporal_store(v, o + b * SAMPLE);
        }
    }
}

extern "C" void kernel_launch(void* const* d_in, const int* in_sizes, int n_in,
                              void* d_out, int out_size, void* d_ws, size_t ws_size,
                              hipStream_t stream) {
    const f32x4* vol = (const f32x4*)d_in[0];
    const f32x4* msk = (const f32x4*)d_in[1];
    const f32x4* skl = (const f32x4*)d_in[2];
    const int* koefs  = (const int*)d_in[3];
    f32x4* out = (f32x4*)d_out;

    rot90_gather_kernel<<<BLOCKS, TPB, 0, stream>>>(vol, msk, skl, koefs, out);
}